// Round 5
// baseline (25.693 us; speedup 1.0000x reference)
//
#include <hip/hip_runtime.h>

// Problem constants (B=1)
#define H 8
#define S 4096
#define D 64          // D1 == D2 == 64
#define C 64          // chunk length
#define NC (S / C)    // 64 chunks per head
#define PITCH 72      // bf16 LDS row pitch (144B, 16B-aligned, 4-bank rotation)

typedef short bf16x8 __attribute__((ext_vector_type(8)));
typedef float f32x4 __attribute__((ext_vector_type(4)));
typedef unsigned uint4v __attribute__((ext_vector_type(4)));

struct alignas(16) F4 { float v[4]; };

__device__ inline unsigned short rne_bf16(float x) {
  unsigned u = __builtin_bit_cast(unsigned, x);
  unsigned r = u + 0x7fffu + ((u >> 16) & 1u);
  return (unsigned short)(r >> 16);
}
__device__ inline float bf16_to_f(unsigned hw) {
  return __builtin_bit_cast(float, hw << 16);
}

// ---------------------------------------------------------------------------
// Kernel 1: per-chunk local state via MFMA, stored TRANSPOSED as bf16:
//   wsKV[h][ch][c][a] = bf16( sum over chunk of v[i][c] * k_bar[i][a] )
// Staging: column-strided coalesced loads -> quantize -> bf16 LDS (no f32 LDS).
// ---------------------------------------------------------------------------
__global__ __launch_bounds__(256) void k_chunk_sums(
    const float* __restrict__ k, const float* __restrict__ v,
    const float* __restrict__ coef_k, unsigned short* __restrict__ wsKV) {
  const int ch = blockIdx.x, h = blockIdx.y, t = threadIdx.x;
  __shared__ alignas(16) short kT[D * PITCH];   // k_bar^T [a][i]
  __shared__ alignas(16) short vT[D * PITCH];   // v^T     [c][i]

  const float* kp = k + (size_t)(h * S + ch * C) * D;
  const float* vp = v + (size_t)(h * S + ch * C) * D;
  const float* ck = coef_k + h * S + ch * C;

  const int w = t >> 6, col = t & 63;
  // waves 0,1 -> kT (i-halves 0,32); waves 2,3 -> vT
  {
    const int i0 = (w & 1) * 32;
    const bool isK = (w < 2);
    const float* src = isK ? kp : vp;
    short* dstT = isK ? kT : vT;
    unsigned pr[16];
#pragma unroll
    for (int u2 = 0; u2 < 16; ++u2) {
      float x0 = src[(i0 + 2 * u2) * D + col];
      float x1 = src[(i0 + 2 * u2 + 1) * D + col];
      if (isK) { x0 *= ck[i0 + 2 * u2]; x1 *= ck[i0 + 2 * u2 + 1]; }
      pr[u2] = (unsigned)rne_bf16(x0) | ((unsigned)rne_bf16(x1) << 16);
    }
#pragma unroll
    for (int g = 0; g < 4; ++g) {
      uint4v wv = {pr[4 * g], pr[4 * g + 1], pr[4 * g + 2], pr[4 * g + 3]};
      *reinterpret_cast<uint4v*>(&dstT[col * PITCH + i0 + 8 * g]) = wv;
    }
  }
  __syncthreads();

  // MFMA: wave w owns output rows c = 16w..16w+15; n-tiles over a
  const int lane = t & 63;
  const int arow = lane & 15, kg = lane >> 4;
  const int abase = (16 * w + arow) * PITCH + 8 * kg;
  bf16x8 a0 = *reinterpret_cast<const bf16x8*>(&vT[abase]);
  bf16x8 a1 = *reinterpret_cast<const bf16x8*>(&vT[abase + 32]);
  unsigned short* dst = wsKV + (size_t)(h * NC + ch) * (D * D);
#pragma unroll
  for (int n = 0; n < 4; ++n) {
    const int bb = (16 * n + arow) * PITCH + 8 * kg;
    bf16x8 b0 = *reinterpret_cast<const bf16x8*>(&kT[bb]);
    bf16x8 b1 = *reinterpret_cast<const bf16x8*>(&kT[bb + 32]);
    f32x4 z = {0.f, 0.f, 0.f, 0.f};
    z = __builtin_amdgcn_mfma_f32_16x16x32_bf16(a0, b0, z, 0, 0, 0);
    z = __builtin_amdgcn_mfma_f32_16x16x32_bf16(a1, b1, z, 0, 0, 0);
#pragma unroll
    for (int r = 0; r < 4; ++r)
      dst[(16 * w + 4 * kg + r) * D + 16 * n + arow] = rne_bf16(z[r]);
  }
}

// ---------------------------------------------------------------------------
// Kernel 2: exclusive prefix scan across chunks (per head), bf16 in/out,
// f32 running sum. 2 elements per thread (dword), 32-deep batching.
// ---------------------------------------------------------------------------
__global__ __launch_bounds__(64) void k_scan(unsigned* __restrict__ wsKV) {
  const int seg = blockIdx.x, h = blockIdx.y, t = threadIdx.x;
  const int e0 = seg * 64 + t;               // dword index within 2048-dword matrix
  float run0 = 0.f, run1 = 0.f;
  for (int base = 0; base < NC; base += 32) {
    unsigned x[32];
#pragma unroll
    for (int u = 0; u < 32; ++u)
      x[u] = wsKV[(size_t)(h * NC + base + u) * 2048 + e0];
#pragma unroll
    for (int u = 0; u < 32; ++u) {
      wsKV[(size_t)(h * NC + base + u) * 2048 + e0] =
          (unsigned)rne_bf16(run0) | ((unsigned)rne_bf16(run1) << 16);
      run0 += bf16_to_f(x[u] & 0xffffu);
      run1 += bf16_to_f(x[u] >> 16);
    }
  }
}

// ---------------------------------------------------------------------------
// Kernel 3: per-chunk output via MFMA 16x16x32 bf16.
//   A = tril(q_bar K_bar^T);  O = q_bar*S0 + A*V;  rmsnorm(O).
// Single barrier; vT from column-strided coalesced global loads; Ab wave-private.
// ---------------------------------------------------------------------------
__global__ __launch_bounds__(256) void k_chunk_out(
    const float* __restrict__ q, const float* __restrict__ k,
    const float* __restrict__ v,
    const float* __restrict__ coef_q, const float* __restrict__ coef_k,
    const float* __restrict__ mask_normer,
    const unsigned short* __restrict__ wsKV, float* __restrict__ out) {
  const int ch = blockIdx.x, h = blockIdx.y, t = threadIdx.x;
  __shared__ alignas(16) short qb[C * PITCH];    // q_bar  [i][a]
  __shared__ alignas(16) short kbf[C * PITCH];   // k_bar  [j][a]
  __shared__ alignas(16) short s0b[D * PITCH];   // S0     [c][a]
  __shared__ alignas(16) short vT[D * PITCH];    // v^T    [c][j]
  __shared__ alignas(16) short Ab[C * PITCH];    // A      [i][j]

  const size_t base = (size_t)(h * S + ch * C) * D;
  const float* qp = q + base;
  const float* kp = k + base;
  const float* vp = v + base;
  const float* cq = coef_q + h * S + ch * C;
  const float* ck = coef_k + h * S + ch * C;
  const float* mn = mask_normer + h * S + ch * C;
  const unsigned short* s0p = wsKV + (size_t)(h * NC + ch) * (D * D);

  // ---- q/k/s0 staging: thread t -> row t>>2, col-group (t&3)*16
  {
    const int i = t >> 2, c0 = (t & 3) * 16;
    const float sq = cq[i] / mn[i];
    const float sk = ck[i];
#pragma unroll
    for (int g = 0; g < 2; ++g) {
      bf16x8 wq, wk;
#pragma unroll
      for (int u0 = 0; u0 < 8; u0 += 4) {
        F4 qv = *reinterpret_cast<const F4*>(qp + i * D + c0 + 8 * g + u0);
        F4 kv = *reinterpret_cast<const F4*>(kp + i * D + c0 + 8 * g + u0);
#pragma unroll
        for (int u = 0; u < 4; ++u) {
          wq[u0 + u] = (short)rne_bf16(qv.v[u] * sq);
          wk[u0 + u] = (short)rne_bf16(kv.v[u] * sk);
        }
      }
      *reinterpret_cast<bf16x8*>(&qb[i * PITCH + c0 + 8 * g]) = wq;
      *reinterpret_cast<bf16x8*>(&kbf[i * PITCH + c0 + 8 * g]) = wk;
      bf16x8 ws = *reinterpret_cast<const bf16x8*>(s0p + i * D + c0 + 8 * g);
      *reinterpret_cast<bf16x8*>(&s0b[i * PITCH + c0 + 8 * g]) = ws;
    }
  }
  // ---- vT staging: thread owns column c=t&63, i-range 16*(t>>6) (coalesced)
  {
    const int c = t & 63, i0 = 16 * (t >> 6);
    unsigned pr[8];
#pragma unroll
    for (int u2 = 0; u2 < 8; ++u2) {
      float x0 = vp[(size_t)(i0 + 2 * u2) * D + c];
      float x1 = vp[(size_t)(i0 + 2 * u2 + 1) * D + c];
      pr[u2] = (unsigned)rne_bf16(x0) | ((unsigned)rne_bf16(x1) << 16);
    }
#pragma unroll
    for (int g = 0; g < 2; ++g) {
      uint4v wv = {pr[4 * g], pr[4 * g + 1], pr[4 * g + 2], pr[4 * g + 3]};
      *reinterpret_cast<uint4v*>(&vT[c * PITCH + i0 + 8 * g]) = wv;
    }
  }
  __syncthreads();

  const int lane = t & 63, w = t >> 6;
  const int arow = lane & 15, kg = lane >> 4;
  const int rbase = (16 * w + arow) * PITCH + 8 * kg;

  // q A-fragments (reused across both stages)
  bf16x8 qa0 = *reinterpret_cast<const bf16x8*>(&qb[rbase]);
  bf16x8 qa1 = *reinterpret_cast<const bf16x8*>(&qb[rbase + 32]);

  // ---- A-stage: wave w computes rows 16w..16w+15, all 4 col-tiles
  {
    f32x4 accA[4];
#pragma unroll
    for (int n = 0; n < 4; ++n) {
      const int bb = (16 * n + arow) * PITCH + 8 * kg;
      bf16x8 b0 = *reinterpret_cast<const bf16x8*>(&kbf[bb]);
      bf16x8 b1 = *reinterpret_cast<const bf16x8*>(&kbf[bb + 32]);
      f32x4 z = {0.f, 0.f, 0.f, 0.f};
      z = __builtin_amdgcn_mfma_f32_16x16x32_bf16(qa0, b0, z, 0, 0, 0);
      z = __builtin_amdgcn_mfma_f32_16x16x32_bf16(qa1, b1, z, 0, 0, 0);
      accA[n] = z;
    }
#pragma unroll
    for (int n = 0; n < 4; ++n)
#pragma unroll
      for (int r = 0; r < 4; ++r) {
        int i = 4 * kg + r;
        int j = 16 * n + arow;
        float x = (j <= 16 * w + i) ? accA[n][r] : 0.f;
        Ab[(16 * w + i) * PITCH + j] = (short)rne_bf16(x);
      }
  }
  // Ab rows 16w.. are wave-private: same-wave read-after-write, no barrier.

  // ---- O-stage
  bf16x8 aa0 = *reinterpret_cast<const bf16x8*>(&Ab[rbase]);
  bf16x8 aa1 = *reinterpret_cast<const bf16x8*>(&Ab[rbase + 32]);
  f32x4 accO[4];
#pragma unroll
  for (int n = 0; n < 4; ++n) {
    const int bb = (16 * n + arow) * PITCH + 8 * kg;
    bf16x8 h0 = *reinterpret_cast<const bf16x8*>(&s0b[bb]);
    bf16x8 h1 = *reinterpret_cast<const bf16x8*>(&s0b[bb + 32]);
    bf16x8 v0 = *reinterpret_cast<const bf16x8*>(&vT[bb]);
    bf16x8 v1 = *reinterpret_cast<const bf16x8*>(&vT[bb + 32]);
    f32x4 z = {0.f, 0.f, 0.f, 0.f};
    z = __builtin_amdgcn_mfma_f32_16x16x32_bf16(qa0, h0, z, 0, 0, 0);
    z = __builtin_amdgcn_mfma_f32_16x16x32_bf16(qa1, h1, z, 0, 0, 0);
    z = __builtin_amdgcn_mfma_f32_16x16x32_bf16(aa0, v0, z, 0, 0, 0);
    z = __builtin_amdgcn_mfma_f32_16x16x32_bf16(aa1, v1, z, 0, 0, 0);
    accO[n] = z;
  }

  // ---- epilogue: rmsnorm per row (row lives in one quarter-wave)
  float* op = out + base;
#pragma unroll
  for (int r = 0; r < 4; ++r) {
    const int i = 16 * w + 4 * kg + r;
    float ss = 0.f;
#pragma unroll
    for (int n = 0; n < 4; ++n) ss += accO[n][r] * accO[n][r];
#pragma unroll
    for (int off = 1; off < 16; off <<= 1) ss += __shfl_xor(ss, off);
    const float sc = rsqrtf(ss * (1.0f / D) + 1e-6f);
#pragma unroll
    for (int n = 0; n < 4; ++n)
      op[(size_t)i * D + 16 * n + arow] = accO[n][r] * sc;
  }
}

// ---------------------------------------------------------------------------
extern "C" void kernel_launch(void* const* d_in, const int* in_sizes, int n_in,
                              void* d_out, int out_size, void* d_ws, size_t ws_size,
                              hipStream_t stream) {
  (void)in_sizes; (void)n_in; (void)out_size; (void)ws_size;
  const float* q  = (const float*)d_in[0];
  const float* k  = (const float*)d_in[1];
  const float* v  = (const float*)d_in[2];
  const float* cq = (const float*)d_in[3];
  const float* ck = (const float*)d_in[4];
  const float* mn = (const float*)d_in[5];
  float* out = (float*)d_out;

  unsigned short* wsKV = (unsigned short*)d_ws;   // H*NC*D*D bf16 (4 MiB)

  k_chunk_sums<<<dim3(NC, H), dim3(256), 0, stream>>>(k, v, ck, wsKV);
  k_scan<<<dim3(32, H), dim3(64), 0, stream>>>((unsigned*)d_ws);
  k_chunk_out<<<dim3(NC, H), dim3(256), 0, stream>>>(q, k, v, cq, ck, mn, wsKV, out);
}